// Round 6
// baseline (416.551 us; speedup 1.0000x reference)
//
#include <hip/hip_runtime.h>
#include <hip/hip_fp16.h>
#include <cstdint>
#include <cstddef>

#define N_NODES 50000
#define N_EDGES 800000
#define DIN_    768
#define H_DIM   128
#define N_REL   3
#define BETA_F  0.05f
#define SLOPE_F 0.2f

static inline int cdiv(int a, int b) { return (a + b - 1) / b; }

typedef __attribute__((ext_vector_type(8))) short bf16x8;
typedef __attribute__((ext_vector_type(8))) unsigned short u16x8;
typedef __attribute__((ext_vector_type(4))) float f32x4;

__device__ __forceinline__ unsigned short f2bf(float f) {
  unsigned u = __builtin_bit_cast(unsigned, f);
  unsigned r = (u + 0x7fffu + ((u >> 16) & 1u)) >> 16;
  return (unsigned short)r;
}
__device__ __forceinline__ float bf2f(unsigned short h) {
  unsigned u = ((unsigned)h) << 16;
  return __builtin_bit_cast(float, u);
}

// ---------------- CSR build ----------------
__global__ void k_count(const int* __restrict__ dst, int* __restrict__ deg, int E) {
  int e = blockIdx.x * blockDim.x + threadIdx.x;
  if (e < E) atomicAdd(&deg[dst[e]], 1);
}

__global__ __launch_bounds__(256) void k_scan1(const int* __restrict__ deg,
                                               int* __restrict__ part, int n) {
  __shared__ int wsum[4];
  int i = blockIdx.x * 256 + threadIdx.x;
  int lane = threadIdx.x & 63, w = threadIdx.x >> 6;
  int v = (i < n) ? deg[i] : 0;
  #pragma unroll
  for (int d = 32; d > 0; d >>= 1) v += __shfl_xor(v, d);
  if (lane == 0) wsum[w] = v;
  __syncthreads();
  if (threadIdx.x == 0) part[blockIdx.x] = wsum[0] + wsum[1] + wsum[2] + wsum[3];
}

__global__ __launch_bounds__(256) void k_scan2(int* __restrict__ part,
                                               int* __restrict__ off, int nb, int n) {
  __shared__ int sh[256];
  int t = threadIdx.x;
  int v = (t < nb) ? part[t] : 0;
  int incl = v;
  sh[t] = incl;
  __syncthreads();
  #pragma unroll
  for (int d = 1; d < 256; d <<= 1) {
    int u = (t >= d) ? sh[t - d] : 0;
    __syncthreads();
    sh[t] += u;
    __syncthreads();
  }
  incl = sh[t];
  if (t < nb) part[t] = incl - v;
  if (t == nb - 1) off[n] = incl;
}

__global__ __launch_bounds__(256) void k_scan3(const int* __restrict__ deg,
                                               const int* __restrict__ part,
                                               int* __restrict__ off,
                                               int* __restrict__ cur, int n) {
  __shared__ int wsum[4];
  int i = blockIdx.x * 256 + threadIdx.x;
  int lane = threadIdx.x & 63, w = threadIdx.x >> 6;
  int v = (i < n) ? deg[i] : 0;
  int incl = v;
  #pragma unroll
  for (int d = 1; d < 64; d <<= 1) {
    int u = __shfl_up(incl, d);
    if (lane >= d) incl += u;
  }
  if (lane == 63) wsum[w] = incl;
  __syncthreads();
  int woff = 0;
  #pragma unroll
  for (int k = 0; k < 4; ++k) woff += (k < w) ? wsum[k] : 0;
  int ex = incl - v + woff + part[blockIdx.x];
  if (i < n) { off[i] = ex; cur[i] = ex; }
}

__global__ void k_fill(const int* __restrict__ dst, int* __restrict__ cur,
                       int* __restrict__ csr, int E) {
  int e = blockIdx.x * blockDim.x + threadIdx.x;
  if (e < E) {
    int p = atomicAdd(&cur[dst[e]], 1);
    csr[p] = e;
  }
}

// ---------------- rel scores ----------------
__global__ __launch_bounds__(128) void k_relscore(const float* __restrict__ rel,
                                                  const float* __restrict__ Wr,
                                                  const float* __restrict__ a,
                                                  float* __restrict__ rs) {
  __shared__ float red[128];
  int k = threadIdx.x;
  for (int t = 0; t < N_REL; ++t) {
    float p = 0.f;
    #pragma unroll
    for (int j = 0; j < 32; ++j) p += rel[t * 32 + j] * Wr[j * H_DIM + k];
    red[k] = p * a[2 * H_DIM + k];
    __syncthreads();
    for (int s = 64; s > 0; s >>= 1) {
      if (k < s) red[k] += red[k + s];
      __syncthreads();
    }
    if (k == 0) rs[t] = red[0];
    __syncthreads();
  }
}

// ---------------- weight prep ----------------
__global__ void k_prep(const float* __restrict__ W, int K,
                       short* __restrict__ th, short* __restrict__ tl) {
  int id = blockIdx.x * 256 + threadIdx.x;
  if (id >= K * 128) return;
  int k = id >> 7, c = id & 127;
  float w = W[id];
  unsigned short h = f2bf(w);
  unsigned short l = f2bf(w - bf2f(h));
  th[(size_t)c * K + k] = (short)h;
  tl[(size_t)c * K + k] = (short)l;
}

// ---------------- pipelined split-bf16 MFMA GEMM ----------------
// BM=64, BK=32, double-buffered LDS, reg-prefetch, 1 barrier/iter.
// LDS layout: granule-major planes; plane strides 1088 (A) / 2112 (B)
// chosen ≡64 (mod 128) so write/read bank aliasing is ≤2-way (free).
#define A_PLANE 1088
#define A_ARR   (4 * A_PLANE)          // 4352
#define B_PLANE 2112
#define B_ARR   (4 * B_PLANE)          // 8448
#define B_BASE  (4 * A_ARR)            // 17408
#define SM_TOT  (B_BASE + 4 * B_ARR)   // 51200

template <bool BIASRELU, bool W16>
__global__ __launch_bounds__(256, 3) void k_gemm_mfma(const float* __restrict__ A,
                                                      const short* __restrict__ Bth,
                                                      const short* __restrict__ Btl,
                                                      const float* __restrict__ bias,
                                                      float* __restrict__ C,
                                                      __half* __restrict__ C16,
                                                      int n, int K) {
  __shared__ __align__(16) char sm[SM_TOT];
  int t = threadIdx.x;
  int l = t & 63, wid = t >> 6;
  int wr = wid >> 1, wc = wid & 1;     // wave -> 32-row half, 64-col half
  int lr = l & 15, lk = l >> 4;        // lane -> frag row, k-granule
  int row0 = blockIdx.x * 64;

  // staging maps
  int ar = t >> 2, ag = t & 3;         // A: 64 rows x 4 granules (coalesced 128B/row)
  int bc0 = t >> 2,          bg0 = t & 3;          // B granule 0 (gid = t)
  int bc1 = (256 + t) >> 2,  bg1 = (256 + t) & 3;  // B granule 1 (gid = 256+t)
  int gar = row0 + ar;
  const float* aptr = (gar < n) ? (A + (size_t)gar * K + ag * 8) : nullptr;
  const short* bh0p = Bth + (size_t)bc0 * K + bg0 * 8;
  const short* bh1p = Bth + (size_t)bc1 * K + bg1 * 8;
  const short* bl0p = Btl + (size_t)bc0 * K + bg0 * 8;
  const short* bl1p = Btl + (size_t)bc1 * K + bg1 * 8;

  f32x4 acc[2][4];
  #pragma unroll
  for (int m = 0; m < 2; ++m)
    #pragma unroll
    for (int nn = 0; nn < 4; ++nn) acc[m][nn] = (f32x4)(0.f);

  // prefetch registers
  float4 pa0, pa1;
  u16x8 pbh0, pbh1, pbl0, pbl1;

  const int nt = K >> 5;

  auto load_tile = [&](int it) {
    int k0 = it << 5;
    if (aptr) {
      pa0 = *(const float4*)(aptr + k0);
      pa1 = *(const float4*)(aptr + k0 + 4);
    } else {
      pa0 = make_float4(0.f, 0.f, 0.f, 0.f);
      pa1 = make_float4(0.f, 0.f, 0.f, 0.f);
    }
    pbh0 = *(const u16x8*)(bh0p + k0);
    pbh1 = *(const u16x8*)(bh1p + k0);
    pbl0 = *(const u16x8*)(bl0p + k0);
    pbl1 = *(const u16x8*)(bl1p + k0);
  };

  auto write_tile = [&](int buf) {
    float f[8] = {pa0.x, pa0.y, pa0.z, pa0.w, pa1.x, pa1.y, pa1.z, pa1.w};
    u16x8 hv, lv;
    #pragma unroll
    for (int j = 0; j < 8; ++j) {
      unsigned short h = f2bf(f[j]);
      hv[j] = h;
      lv[j] = f2bf(f[j] - bf2f(h));
    }
    char* aH = sm + (buf * 2 + 0) * A_ARR + ag * A_PLANE + ar * 16;
    char* aL = sm + (buf * 2 + 1) * A_ARR + ag * A_PLANE + ar * 16;
    *(u16x8*)aH = hv;
    *(u16x8*)aL = lv;
    char* bH = sm + B_BASE + (buf * 2 + 0) * B_ARR;
    char* bL = sm + B_BASE + (buf * 2 + 1) * B_ARR;
    *(u16x8*)(bH + bg0 * B_PLANE + bc0 * 16) = pbh0;
    *(u16x8*)(bH + bg1 * B_PLANE + bc1 * 16) = pbh1;
    *(u16x8*)(bL + bg0 * B_PLANE + bc0 * 16) = pbl0;
    *(u16x8*)(bL + bg1 * B_PLANE + bc1 * 16) = pbl1;
  };

  // prologue
  load_tile(0);
  write_tile(0);
  __syncthreads();

  int cur = 0;
  for (int it = 0; it < nt; ++it) {
    bool more = (it + 1 < nt);
    if (more) load_tile(it + 1);       // issue early — hides under MFMA

    // MFMA phase on buf[cur]
    {
      const char* aH = sm + (cur * 2 + 0) * A_ARR + lk * A_PLANE;
      const char* aL = sm + (cur * 2 + 1) * A_ARR + lk * A_PLANE;
      const char* bH = sm + B_BASE + (cur * 2 + 0) * B_ARR + lk * B_PLANE;
      const char* bL = sm + B_BASE + (cur * 2 + 1) * B_ARR + lk * B_PLANE;
      bf16x8 ah[2], al[2], bh[4], bl[4];
      #pragma unroll
      for (int m = 0; m < 2; ++m) {
        int r = wr * 32 + m * 16 + lr;
        ah[m] = *(const bf16x8*)(aH + r * 16);
        al[m] = *(const bf16x8*)(aL + r * 16);
      }
      #pragma unroll
      for (int nn = 0; nn < 4; ++nn) {
        int c = wc * 64 + nn * 16 + lr;
        bh[nn] = *(const bf16x8*)(bH + c * 16);
        bl[nn] = *(const bf16x8*)(bL + c * 16);
      }
      #pragma unroll
      for (int m = 0; m < 2; ++m)
        #pragma unroll
        for (int nn = 0; nn < 4; ++nn) {
          acc[m][nn] = __builtin_amdgcn_mfma_f32_16x16x32_bf16(ah[m], bh[nn], acc[m][nn], 0, 0, 0);
          acc[m][nn] = __builtin_amdgcn_mfma_f32_16x16x32_bf16(ah[m], bl[nn], acc[m][nn], 0, 0, 0);
          acc[m][nn] = __builtin_amdgcn_mfma_f32_16x16x32_bf16(al[m], bh[nn], acc[m][nn], 0, 0, 0);
        }
    }

    if (more) write_tile(cur ^ 1);     // vmcnt-wait + convert happen after MFMA
    __syncthreads();
    cur ^= 1;
  }

  // epilogue: C/D layout col=lane&15, row=(lane>>4)*4+q
  #pragma unroll
  for (int m = 0; m < 2; ++m) {
    int rbase = row0 + wr * 32 + m * 16 + lk * 4;
    #pragma unroll
    for (int nn = 0; nn < 4; ++nn) {
      int c = wc * 64 + nn * 16 + lr;
      #pragma unroll
      for (int q = 0; q < 4; ++q) {
        int r = rbase + q;
        if (r < n) {
          float v = acc[m][nn][q];
          if (BIASRELU) {
            v += bias[c];
            v = v > 0.f ? v : 0.f;
          }
          C[(size_t)r * 128 + c] = v;
          if (W16) C16[(size_t)r * 128 + c] = __float2half(v);
        }
      }
    }
  }
}

// ---------------- per-node scores ----------------
__global__ __launch_bounds__(256) void k_scores(const float* __restrict__ h,
                                                const float* __restrict__ a,
                                                float* __restrict__ ni,
                                                float* __restrict__ nj, int n) {
  int lane = threadIdx.x & 63;
  int w = threadIdx.x >> 6;
  int row = blockIdx.x * 4 + w;
  if (row >= n) return;
  float2 v = ((const float2*)(h + (size_t)row * H_DIM))[lane];
  float2 ai = ((const float2*)a)[lane];
  float2 aj = ((const float2*)(a + H_DIM))[lane];
  float si = v.x * ai.x + v.y * ai.y;
  float sj = v.x * aj.x + v.y * aj.y;
  #pragma unroll
  for (int d = 32; d > 0; d >>= 1) {
    si += __shfl_xor(si, d);
    sj += __shfl_xor(sj, d);
  }
  if (lane == 0) { ni[row] = si; nj[row] = sj; }
}

// ---------------- edge logits ----------------
__global__ void k_logit(const int* __restrict__ src, const int* __restrict__ dst,
                        const int* __restrict__ et,
                        const float* __restrict__ ni, const float* __restrict__ nj,
                        const float* __restrict__ rs,
                        float* __restrict__ logit, int E) {
  int e = blockIdx.x * blockDim.x + threadIdx.x;
  if (e >= E) return;
  float v = ni[dst[e]] + nj[src[e]] + rs[et[e]];
  logit[e] = v > 0.f ? v : SLOPE_F * v;
}

// ---------------- per-dst softmax + aggregate (fp16 gather) + ELU ----------------
template <int LAYER>
__global__ __launch_bounds__(128) void k_aggregate(const int* __restrict__ off,
                                                   const int* __restrict__ csr,
                                                   const int* __restrict__ src,
                                                   const float* __restrict__ logit,
                                                   const __half* __restrict__ h16,
                                                   float* __restrict__ alpha_io,
                                                   float* __restrict__ hout, int n) {
  __shared__ float l_red[2];
  __shared__ float l_alpha[128];
  __shared__ int   l_src[128];
  int nid = blockIdx.x;
  int t = threadIdx.x;
  int lane = t & 63;
  int w = t >> 6;
  int start = off[nid];
  int deg = off[nid + 1] - start;
  float hv = 0.f;
  if (deg > 0) {
    float m = -INFINITY;
    for (int k = t; k < deg; k += 128) m = fmaxf(m, logit[csr[start + k]]);
    #pragma unroll
    for (int d = 32; d > 0; d >>= 1) m = fmaxf(m, __shfl_xor(m, d));
    if (lane == 0) l_red[w] = m;
    __syncthreads();
    m = fmaxf(l_red[0], l_red[1]);
    __syncthreads();
    float s = 0.f;
    for (int k = t; k < deg; k += 128) s += expf(logit[csr[start + k]] - m);
    #pragma unroll
    for (int d = 32; d > 0; d >>= 1) s += __shfl_xor(s, d);
    if (lane == 0) l_red[w] = s;
    __syncthreads();
    float denom = l_red[0] + l_red[1] + 1e-16f;
    for (int base = 0; base < deg; base += 128) {
      int kk = base + t;
      if (kk < deg) {
        int e = csr[start + kk];
        float al = expf(logit[e] - m) / denom;
        if (LAYER == 1) {
          al = al * (1.f - BETA_F) + BETA_F * alpha_io[e];
        } else {
          alpha_io[e] = al;
        }
        l_alpha[t] = al;
        l_src[t] = src[e];
      }
      __syncthreads();
      int cnt = deg - base; if (cnt > 128) cnt = 128;
      #pragma unroll 4
      for (int k = 0; k < cnt; ++k)
        hv += l_alpha[k] * __half2float(h16[(size_t)l_src[k] * H_DIM + t]);
      __syncthreads();
    }
  }
  hout[(size_t)nid * H_DIM + t] = hv > 0.f ? hv : expm1f(hv);
}

// ---------------- final 128->2 projection ----------------
__global__ __launch_bounds__(256) void k_out(const float* __restrict__ P,
                                             const float* __restrict__ ow,
                                             const float* __restrict__ ob,
                                             float* __restrict__ out, int n) {
  int lane = threadIdx.x & 63;
  int w = threadIdx.x >> 6;
  int row = blockIdx.x * 4 + w;
  if (row >= n) return;
  float2 v  = ((const float2*)(P + (size_t)row * H_DIM))[lane];
  float2 w0 = ((const float2*)ow)[2 * lane];
  float2 w1 = ((const float2*)ow)[2 * lane + 1];
  float s0 = v.x * w0.x + v.y * w1.x;
  float s1 = v.x * w0.y + v.y * w1.y;
  #pragma unroll
  for (int d = 32; d > 0; d >>= 1) {
    s0 += __shfl_xor(s0, d);
    s1 += __shfl_xor(s1, d);
  }
  if (lane == 0) {
    out[row * 2]     = s0 + ob[0];
    out[row * 2 + 1] = s1 + ob[1];
  }
}

extern "C" void kernel_launch(void* const* d_in, const int* in_sizes, int n_in,
                              void* d_out, int out_size, void* d_ws, size_t ws_size,
                              hipStream_t stream) {
  const float* x      = (const float*)d_in[0];
  const int*   ei     = (const int*)d_in[1];
  const int*   et     = (const int*)d_in[2];
  const float* W0     = (const float*)d_in[3];
  const float* Wr0    = (const float*)d_in[4];
  const float* a0     = (const float*)d_in[5];
  const float* rel0   = (const float*)d_in[6];
  const float* W1     = (const float*)d_in[7];
  const float* Wr1    = (const float*)d_in[8];
  const float* a1     = (const float*)d_in[9];
  const float* rel1   = (const float*)d_in[10];
  const float* pool_w = (const float*)d_in[11];
  const float* pool_b = (const float*)d_in[12];
  const float* out_w  = (const float*)d_in[13];
  const float* out_b  = (const float*)d_in[14];

  const int* src = ei;
  const int* dst = ei + N_EDGES;

  char* p = (char*)d_ws;
  auto take = [&](size_t bytes) {
    char* r = p;
    p += (bytes + 511) & ~(size_t)511;
    return r;
  };
  int*   deg    = (int*)take((size_t)N_NODES * 4);
  int*   off    = (int*)take((size_t)(N_NODES + 1) * 4);
  int*   cur    = (int*)take((size_t)N_NODES * 4);
  int*   part   = (int*)take((size_t)256 * 4);
  int*   csr    = (int*)take((size_t)N_EDGES * 4);
  float* logit  = (float*)take((size_t)N_EDGES * 4);
  float* alpha0 = (float*)take((size_t)N_EDGES * 4);
  float* ni     = (float*)take((size_t)N_NODES * 4);
  float* nj     = (float*)take((size_t)N_NODES * 4);
  float* rs     = (float*)take(256);
  short* wt0h   = (short*)take((size_t)DIN_ * 128 * 2);
  short* wt0l   = (short*)take((size_t)DIN_ * 128 * 2);
  short* wt1h   = (short*)take((size_t)128 * 128 * 2);
  short* wt1l   = (short*)take((size_t)128 * 128 * 2);
  short* wph    = (short*)take((size_t)128 * 128 * 2);
  short* wpl    = (short*)take((size_t)128 * 128 * 2);
  float* big1   = (float*)take((size_t)N_NODES * H_DIM * 4);
  float* big2   = (float*)take((size_t)N_NODES * H_DIM * 4);
  __half* h16   = (__half*)take((size_t)N_NODES * H_DIM * 2);

  const int EB = cdiv(N_EDGES, 256);
  const int GB = cdiv(N_NODES, 64);
  const int SB = cdiv(N_NODES, 256);

  // ---- CSR build ----
  hipMemsetAsync(deg, 0, (size_t)N_NODES * 4, stream);
  k_count<<<EB, 256, 0, stream>>>(dst, deg, N_EDGES);
  k_scan1<<<SB, 256, 0, stream>>>(deg, part, N_NODES);
  k_scan2<<<1, 256, 0, stream>>>(part, off, SB, N_NODES);
  k_scan3<<<SB, 256, 0, stream>>>(deg, part, off, cur, N_NODES);
  k_fill<<<EB, 256, 0, stream>>>(dst, cur, csr, N_EDGES);

  // ---- weight prep ----
  k_prep<<<cdiv(DIN_ * 128, 256), 256, 0, stream>>>(W0, DIN_, wt0h, wt0l);
  k_prep<<<cdiv(128 * 128, 256), 256, 0, stream>>>(W1, 128, wt1h, wt1l);
  k_prep<<<cdiv(128 * 128, 256), 256, 0, stream>>>(pool_w, 128, wph, wpl);

  // ---- layer 0 ----
  k_relscore<<<1, 128, 0, stream>>>(rel0, Wr0, a0, rs);
  k_gemm_mfma<false, true><<<GB, 256, 0, stream>>>(x, wt0h, wt0l, nullptr, big1, h16, N_NODES, DIN_);
  k_scores<<<cdiv(N_NODES, 4), 256, 0, stream>>>(big1, a0, ni, nj, N_NODES);
  k_logit<<<EB, 256, 0, stream>>>(src, dst, et, ni, nj, rs, logit, N_EDGES);
  k_aggregate<0><<<N_NODES, 128, 0, stream>>>(off, csr, src, logit, h16, alpha0, big2, N_NODES);

  // ---- layer 1 ----
  k_relscore<<<1, 128, 0, stream>>>(rel1, Wr1, a1, rs);
  k_gemm_mfma<false, true><<<GB, 256, 0, stream>>>(big2, wt1h, wt1l, nullptr, big1, h16, N_NODES, 128);
  k_scores<<<cdiv(N_NODES, 4), 256, 0, stream>>>(big1, a1, ni, nj, N_NODES);
  k_logit<<<EB, 256, 0, stream>>>(src, dst, et, ni, nj, rs, logit, N_EDGES);
  k_aggregate<1><<<N_NODES, 128, 0, stream>>>(off, csr, src, logit, h16, alpha0, big2, N_NODES);

  // ---- head ----
  k_gemm_mfma<true, false><<<GB, 256, 0, stream>>>(big2, wph, wpl, pool_b, big1, nullptr, N_NODES, 128);
  k_out<<<cdiv(N_NODES, 4), 256, 0, stream>>>(big1, out_w, out_b, (float*)d_out, N_NODES);
}

// Round 7
// 395.069 us; speedup vs baseline: 1.0544x; 1.0544x over previous
//
#include <hip/hip_runtime.h>
#include <hip/hip_fp16.h>
#include <cstdint>
#include <cstddef>

#define N_NODES 50000
#define N_EDGES 800000
#define DIN_    768
#define H_DIM   128
#define N_REL   3
#define BETA_F  0.05f
#define SLOPE_F 0.2f

static inline int cdiv(int a, int b) { return (a + b - 1) / b; }

typedef __attribute__((ext_vector_type(8))) short bf16x8;
typedef __attribute__((ext_vector_type(8))) unsigned short u16x8;
typedef __attribute__((ext_vector_type(4))) float f32x4;

__device__ __forceinline__ unsigned short f2bf(float f) {
  unsigned u = __builtin_bit_cast(unsigned, f);
  unsigned r = (u + 0x7fffu + ((u >> 16) & 1u)) >> 16;
  return (unsigned short)r;
}
__device__ __forceinline__ float bf2f(unsigned short h) {
  unsigned u = ((unsigned)h) << 16;
  return __builtin_bit_cast(float, u);
}

#define GLOAD_LDS16(g, s) __builtin_amdgcn_global_load_lds( \
    (const __attribute__((address_space(1))) void*)(g),      \
    (__attribute__((address_space(3))) void*)(s), 16, 0, 0)

// ---------------- CSR build ----------------
__global__ void k_count(const int* __restrict__ dst, int* __restrict__ deg, int E) {
  int e = blockIdx.x * blockDim.x + threadIdx.x;
  if (e < E) atomicAdd(&deg[dst[e]], 1);
}

__global__ __launch_bounds__(256) void k_scan1(const int* __restrict__ deg,
                                               int* __restrict__ part, int n) {
  __shared__ int wsum[4];
  int i = blockIdx.x * 256 + threadIdx.x;
  int lane = threadIdx.x & 63, w = threadIdx.x >> 6;
  int v = (i < n) ? deg[i] : 0;
  #pragma unroll
  for (int d = 32; d > 0; d >>= 1) v += __shfl_xor(v, d);
  if (lane == 0) wsum[w] = v;
  __syncthreads();
  if (threadIdx.x == 0) part[blockIdx.x] = wsum[0] + wsum[1] + wsum[2] + wsum[3];
}

__global__ __launch_bounds__(256) void k_scan2(int* __restrict__ part,
                                               int* __restrict__ off, int nb, int n) {
  __shared__ int sh[256];
  int t = threadIdx.x;
  int v = (t < nb) ? part[t] : 0;
  int incl = v;
  sh[t] = incl;
  __syncthreads();
  #pragma unroll
  for (int d = 1; d < 256; d <<= 1) {
    int u = (t >= d) ? sh[t - d] : 0;
    __syncthreads();
    sh[t] += u;
    __syncthreads();
  }
  incl = sh[t];
  if (t < nb) part[t] = incl - v;
  if (t == nb - 1) off[n] = incl;
}

__global__ __launch_bounds__(256) void k_scan3(const int* __restrict__ deg,
                                               const int* __restrict__ part,
                                               int* __restrict__ off,
                                               int* __restrict__ cur, int n) {
  __shared__ int wsum[4];
  int i = blockIdx.x * 256 + threadIdx.x;
  int lane = threadIdx.x & 63, w = threadIdx.x >> 6;
  int v = (i < n) ? deg[i] : 0;
  int incl = v;
  #pragma unroll
  for (int d = 1; d < 64; d <<= 1) {
    int u = __shfl_up(incl, d);
    if (lane >= d) incl += u;
  }
  if (lane == 63) wsum[w] = incl;
  __syncthreads();
  int woff = 0;
  #pragma unroll
  for (int k = 0; k < 4; ++k) woff += (k < w) ? wsum[k] : 0;
  int ex = incl - v + woff + part[blockIdx.x];
  if (i < n) { off[i] = ex; cur[i] = ex; }
}

__global__ void k_fill(const int* __restrict__ dst, int* __restrict__ cur,
                       int* __restrict__ csr, int E) {
  int e = blockIdx.x * blockDim.x + threadIdx.x;
  if (e < E) {
    int p = atomicAdd(&cur[dst[e]], 1);
    csr[p] = e;
  }
}

// ---------------- rel scores ----------------
__global__ __launch_bounds__(128) void k_relscore(const float* __restrict__ rel,
                                                  const float* __restrict__ Wr,
                                                  const float* __restrict__ a,
                                                  float* __restrict__ rs) {
  __shared__ float red[128];
  int k = threadIdx.x;
  for (int t = 0; t < N_REL; ++t) {
    float p = 0.f;
    #pragma unroll
    for (int j = 0; j < 32; ++j) p += rel[t * 32 + j] * Wr[j * H_DIM + k];
    red[k] = p * a[2 * H_DIM + k];
    __syncthreads();
    for (int s = 64; s > 0; s >>= 1) {
      if (k < s) red[k] += red[k + s];
      __syncthreads();
    }
    if (k == 0) rs[t] = red[0];
    __syncthreads();
  }
}

// ---------------- weight prep: W[K][128] -> tiled+swizzled bf16 hi/lo ----------------
// Output layout: tile kt (16KB = 128 cols x 64 k), within tile: col c row of 8
// granules of 16B, granule POSITION p holds logical granule g = p ^ (c&7).
__global__ void k_prep(const float* __restrict__ W, int K,
                       short* __restrict__ th, short* __restrict__ tl) {
  int id = blockIdx.x * 256 + threadIdx.x;
  if (id >= K * 128) return;
  int k = id >> 7, c = id & 127;
  float w = W[id];
  unsigned short h = f2bf(w);
  unsigned short l = f2bf(w - bf2f(h));
  int kt = k >> 6;
  int g = (k >> 3) & 7;
  int j = k & 7;
  int p = g ^ (c & 7);
  size_t pos = ((size_t)(kt * 128 + c) << 6) + (p << 3) + j;
  th[pos] = (short)h;
  tl[pos] = (short)l;
}

// ---------------- m97-style split-bf16 MFMA GEMM ----------------
// BM=64 x BN=128, BK=64, 4 waves, single-buffered 48KB LDS, 2 barriers/iter.
// A staged as raw f32 via global_load_lds with inverse-swizzled per-lane source;
// B staged via linear global_load_lds from pre-swizzled tiled global buffers.
template <bool BIASRELU, bool W16>
__global__ __launch_bounds__(256, 3) void k_gemm_mfma(const float* __restrict__ A,
                                                      const short* __restrict__ Bswh,
                                                      const short* __restrict__ Bswl,
                                                      const float* __restrict__ bias,
                                                      float* __restrict__ C,
                                                      __half* __restrict__ C16,
                                                      int n, int K) {
  __shared__ __align__(16) char Asm[16384];   // [64 r][64 k] f32, 32B-pair swizzle
  __shared__ __align__(16) char Bhs[16384];   // [128 c][64 k] bf16, 16B swizzle
  __shared__ __align__(16) char Bls[16384];
  int t = threadIdx.x;
  int l = t & 63, wid = t >> 6;
  int wr = wid >> 1, wc = wid & 1;
  int lr = l & 15, lk = l >> 4;
  int row0 = blockIdx.x * 64;

  f32x4 acc[2][4];
  #pragma unroll
  for (int m = 0; m < 2; ++m)
    #pragma unroll
    for (int nn = 0; nn < 4; ++nn) acc[m][nn] = (f32x4)(0.f);

  const int nt = K >> 6;

  // precompute per-lane A source row/granule for the 4 staging slots
  int a_r[4], a_gl[4];
  #pragma unroll
  for (int i = 0; i < 4; ++i) {
    int id = (wid * 4 + i) * 64 + l;       // 16B slot index, 0..1023
    int r = id >> 4, s = id & 15;
    int p32 = s >> 1, b = s & 1;
    a_r[i] = r;
    a_gl[i] = (((p32 ^ (r & 7)) << 1) | b); // logical 16B granule (4 floats)
  }

  for (int it = 0; it < nt; ++it) {
    int k0 = it << 6;
    // ---- stage: 12 global_load_lds per wave, nothing else ----
    #pragma unroll
    for (int i = 0; i < 4; ++i) {
      int gr = row0 + a_r[i]; if (gr >= n) gr = n - 1;
      const float* src = A + (size_t)gr * K + k0 + a_gl[i] * 4;
      GLOAD_LDS16(src, Asm + (wid * 4 + i) * 1024);
    }
    const short* bh_t = Bswh + (size_t)it * 8192;
    const short* bl_t = Bswl + (size_t)it * 8192;
    #pragma unroll
    for (int i = 0; i < 4; ++i) {
      int id = (wid * 4 + i) * 64 + l;
      GLOAD_LDS16(bh_t + id * 8, Bhs + (wid * 4 + i) * 1024);
    }
    #pragma unroll
    for (int i = 0; i < 4; ++i) {
      int id = (wid * 4 + i) * 64 + l;
      GLOAD_LDS16(bl_t + id * 8, Bls + (wid * 4 + i) * 1024);
    }
    __syncthreads();   // drains vmcnt; staged data visible

    // ---- compute ----
    #pragma unroll
    for (int kk = 0; kk < 2; ++kk) {
      int q = kk * 4 + lk;                 // logical 32B pair (8 f32 / 8 bf16)
      bf16x8 ah[2], al[2];
      #pragma unroll
      for (int m = 0; m < 2; ++m) {
        int r = wr * 32 + m * 16 + lr;
        const char* ap = Asm + r * 256 + ((q ^ (r & 7)) << 5);
        float4 f0 = *(const float4*)ap;
        float4 f1 = *(const float4*)(ap + 16);
        float ff[8] = {f0.x, f0.y, f0.z, f0.w, f1.x, f1.y, f1.z, f1.w};
        u16x8 hv, lv;
        #pragma unroll
        for (int j = 0; j < 8; ++j) {
          unsigned u = __builtin_bit_cast(unsigned, ff[j]);
          unsigned short h = (unsigned short)(u >> 16);   // truncation: exact split
          hv[j] = h;
          lv[j] = f2bf(ff[j] - bf2f(h));
        }
        ah[m] = __builtin_bit_cast(bf16x8, hv);
        al[m] = __builtin_bit_cast(bf16x8, lv);
      }
      bf16x8 bh[4], bl[4];
      #pragma unroll
      for (int nn = 0; nn < 4; ++nn) {
        int c = wc * 64 + nn * 16 + lr;
        int p = q ^ (c & 7);
        bh[nn] = *(const bf16x8*)(Bhs + c * 128 + p * 16);
        bl[nn] = *(const bf16x8*)(Bls + c * 128 + p * 16);
      }
      #pragma unroll
      for (int m = 0; m < 2; ++m)
        #pragma unroll
        for (int nn = 0; nn < 4; ++nn) {
          acc[m][nn] = __builtin_amdgcn_mfma_f32_16x16x32_bf16(ah[m], bh[nn], acc[m][nn], 0, 0, 0);
          acc[m][nn] = __builtin_amdgcn_mfma_f32_16x16x32_bf16(ah[m], bl[nn], acc[m][nn], 0, 0, 0);
          acc[m][nn] = __builtin_amdgcn_mfma_f32_16x16x32_bf16(al[m], bh[nn], acc[m][nn], 0, 0, 0);
        }
    }
    __syncthreads();   // all reads done before next stage overwrites
  }

  // ---- epilogue: C/D layout col=lane&15, row=(lane>>4)*4+q ----
  #pragma unroll
  for (int m = 0; m < 2; ++m) {
    int rbase = row0 + wr * 32 + m * 16 + lk * 4;
    #pragma unroll
    for (int nn = 0; nn < 4; ++nn) {
      int c = wc * 64 + nn * 16 + lr;
      #pragma unroll
      for (int q = 0; q < 4; ++q) {
        int r = rbase + q;
        if (r < n) {
          float v = acc[m][nn][q];
          if (BIASRELU) {
            v += bias[c];
            v = v > 0.f ? v : 0.f;
          }
          C[(size_t)r * 128 + c] = v;
          if (W16) C16[(size_t)r * 128 + c] = __float2half(v);
        }
      }
    }
  }
}

// ---------------- per-node scores ----------------
__global__ __launch_bounds__(256) void k_scores(const float* __restrict__ h,
                                                const float* __restrict__ a,
                                                float* __restrict__ ni,
                                                float* __restrict__ nj, int n) {
  int lane = threadIdx.x & 63;
  int w = threadIdx.x >> 6;
  int row = blockIdx.x * 4 + w;
  if (row >= n) return;
  float2 v = ((const float2*)(h + (size_t)row * H_DIM))[lane];
  float2 ai = ((const float2*)a)[lane];
  float2 aj = ((const float2*)(a + H_DIM))[lane];
  float si = v.x * ai.x + v.y * ai.y;
  float sj = v.x * aj.x + v.y * aj.y;
  #pragma unroll
  for (int d = 32; d > 0; d >>= 1) {
    si += __shfl_xor(si, d);
    sj += __shfl_xor(sj, d);
  }
  if (lane == 0) { ni[row] = si; nj[row] = sj; }
}

// ---------------- edge logits ----------------
__global__ void k_logit(const int* __restrict__ src, const int* __restrict__ dst,
                        const int* __restrict__ et,
                        const float* __restrict__ ni, const float* __restrict__ nj,
                        const float* __restrict__ rs,
                        float* __restrict__ logit, int E) {
  int e = blockIdx.x * blockDim.x + threadIdx.x;
  if (e >= E) return;
  float v = ni[dst[e]] + nj[src[e]] + rs[et[e]];
  logit[e] = v > 0.f ? v : SLOPE_F * v;
}

// ---------------- per-dst softmax + aggregate (fp16 gather) + ELU ----------------
template <int LAYER>
__global__ __launch_bounds__(128) void k_aggregate(const int* __restrict__ off,
                                                   const int* __restrict__ csr,
                                                   const int* __restrict__ src,
                                                   const float* __restrict__ logit,
                                                   const __half* __restrict__ h16,
                                                   float* __restrict__ alpha_io,
                                                   float* __restrict__ hout, int n) {
  __shared__ float l_red[2];
  __shared__ float l_alpha[128];
  __shared__ int   l_src[128];
  int nid = blockIdx.x;
  int t = threadIdx.x;
  int lane = t & 63;
  int w = t >> 6;
  int start = off[nid];
  int deg = off[nid + 1] - start;
  float hv = 0.f;
  if (deg > 0) {
    float m = -INFINITY;
    for (int k = t; k < deg; k += 128) m = fmaxf(m, logit[csr[start + k]]);
    #pragma unroll
    for (int d = 32; d > 0; d >>= 1) m = fmaxf(m, __shfl_xor(m, d));
    if (lane == 0) l_red[w] = m;
    __syncthreads();
    m = fmaxf(l_red[0], l_red[1]);
    __syncthreads();
    float s = 0.f;
    for (int k = t; k < deg; k += 128) s += expf(logit[csr[start + k]] - m);
    #pragma unroll
    for (int d = 32; d > 0; d >>= 1) s += __shfl_xor(s, d);
    if (lane == 0) l_red[w] = s;
    __syncthreads();
    float denom = l_red[0] + l_red[1] + 1e-16f;
    for (int base = 0; base < deg; base += 128) {
      int kk = base + t;
      if (kk < deg) {
        int e = csr[start + kk];
        float al = expf(logit[e] - m) / denom;
        if (LAYER == 1) {
          al = al * (1.f - BETA_F) + BETA_F * alpha_io[e];
        } else {
          alpha_io[e] = al;
        }
        l_alpha[t] = al;
        l_src[t] = src[e];
      }
      __syncthreads();
      int cnt = deg - base; if (cnt > 128) cnt = 128;
      #pragma unroll 4
      for (int k = 0; k < cnt; ++k)
        hv += l_alpha[k] * __half2float(h16[(size_t)l_src[k] * H_DIM + t]);
      __syncthreads();
    }
  }
  hout[(size_t)nid * H_DIM + t] = hv > 0.f ? hv : expm1f(hv);
}

// ---------------- final 128->2 projection ----------------
__global__ __launch_bounds__(256) void k_out(const float* __restrict__ P,
                                             const float* __restrict__ ow,
                                             const float* __restrict__ ob,
                                             float* __restrict__ out, int n) {
  int lane = threadIdx.x & 63;
  int w = threadIdx.x >> 6;
  int row = blockIdx.x * 4 + w;
  if (row >= n) return;
  float2 v  = ((const float2*)(P + (size_t)row * H_DIM))[lane];
  float2 w0 = ((const float2*)ow)[2 * lane];
  float2 w1 = ((const float2*)ow)[2 * lane + 1];
  float s0 = v.x * w0.x + v.y * w1.x;
  float s1 = v.x * w0.y + v.y * w1.y;
  #pragma unroll
  for (int d = 32; d > 0; d >>= 1) {
    s0 += __shfl_xor(s0, d);
    s1 += __shfl_xor(s1, d);
  }
  if (lane == 0) {
    out[row * 2]     = s0 + ob[0];
    out[row * 2 + 1] = s1 + ob[1];
  }
}

extern "C" void kernel_launch(void* const* d_in, const int* in_sizes, int n_in,
                              void* d_out, int out_size, void* d_ws, size_t ws_size,
                              hipStream_t stream) {
  const float* x      = (const float*)d_in[0];
  const int*   ei     = (const int*)d_in[1];
  const int*   et     = (const int*)d_in[2];
  const float* W0     = (const float*)d_in[3];
  const float* Wr0    = (const float*)d_in[4];
  const float* a0     = (const float*)d_in[5];
  const float* rel0   = (const float*)d_in[6];
  const float* W1     = (const float*)d_in[7];
  const float* Wr1    = (const float*)d_in[8];
  const float* a1     = (const float*)d_in[9];
  const float* rel1   = (const float*)d_in[10];
  const float* pool_w = (const float*)d_in[11];
  const float* pool_b = (const float*)d_in[12];
  const float* out_w  = (const float*)d_in[13];
  const float* out_b  = (const float*)d_in[14];

  const int* src = ei;
  const int* dst = ei + N_EDGES;

  char* p = (char*)d_ws;
  auto take = [&](size_t bytes) {
    char* r = p;
    p += (bytes + 511) & ~(size_t)511;
    return r;
  };
  int*   deg    = (int*)take((size_t)N_NODES * 4);
  int*   off    = (int*)take((size_t)(N_NODES + 1) * 4);
  int*   cur    = (int*)take((size_t)N_NODES * 4);
  int*   part   = (int*)take((size_t)256 * 4);
  int*   csr    = (int*)take((size_t)N_EDGES * 4);
  float* logit  = (float*)take((size_t)N_EDGES * 4);
  float* alpha0 = (float*)take((size_t)N_EDGES * 4);
  float* ni     = (float*)take((size_t)N_NODES * 4);
  float* nj     = (float*)take((size_t)N_NODES * 4);
  float* rs     = (float*)take(256);
  short* wt0h   = (short*)take((size_t)DIN_ * 128 * 2);
  short* wt0l   = (short*)take((size_t)DIN_ * 128 * 2);
  short* wt1h   = (short*)take((size_t)128 * 128 * 2);
  short* wt1l   = (short*)take((size_t)128 * 128 * 2);
  short* wph    = (short*)take((size_t)128 * 128 * 2);
  short* wpl    = (short*)take((size_t)128 * 128 * 2);
  float* big1   = (float*)take((size_t)N_NODES * H_DIM * 4);
  float* big2   = (float*)take((size_t)N_NODES * H_DIM * 4);
  __half* h16   = (__half*)take((size_t)N_NODES * H_DIM * 2);

  const int EB = cdiv(N_EDGES, 256);
  const int GB = cdiv(N_NODES, 64);
  const int SB = cdiv(N_NODES, 256);

  // ---- CSR build ----
  hipMemsetAsync(deg, 0, (size_t)N_NODES * 4, stream);
  k_count<<<EB, 256, 0, stream>>>(dst, deg, N_EDGES);
  k_scan1<<<SB, 256, 0, stream>>>(deg, part, N_NODES);
  k_scan2<<<1, 256, 0, stream>>>(part, off, SB, N_NODES);
  k_scan3<<<SB, 256, 0, stream>>>(deg, part, off, cur, N_NODES);
  k_fill<<<EB, 256, 0, stream>>>(dst, cur, csr, N_EDGES);

  // ---- weight prep (transpose + bf16 hi/lo split + tile/swizzle) ----
  k_prep<<<cdiv(DIN_ * 128, 256), 256, 0, stream>>>(W0, DIN_, wt0h, wt0l);
  k_prep<<<cdiv(128 * 128, 256), 256, 0, stream>>>(W1, 128, wt1h, wt1l);
  k_prep<<<cdiv(128 * 128, 256), 256, 0, stream>>>(pool_w, 128, wph, wpl);

  // ---- layer 0 ----
  k_relscore<<<1, 128, 0, stream>>>(rel0, Wr0, a0, rs);
  k_gemm_mfma<false, true><<<GB, 256, 0, stream>>>(x, wt0h, wt0l, nullptr, big1, h16, N_NODES, DIN_);
  k_scores<<<cdiv(N_NODES, 4), 256, 0, stream>>>(big1, a0, ni, nj, N_NODES);
  k_logit<<<EB, 256, 0, stream>>>(src, dst, et, ni, nj, rs, logit, N_EDGES);
  k_aggregate<0><<<N_NODES, 128, 0, stream>>>(off, csr, src, logit, h16, alpha0, big2, N_NODES);

  // ---- layer 1 ----
  k_relscore<<<1, 128, 0, stream>>>(rel1, Wr1, a1, rs);
  k_gemm_mfma<false, true><<<GB, 256, 0, stream>>>(big2, wt1h, wt1l, nullptr, big1, h16, N_NODES, 128);
  k_scores<<<cdiv(N_NODES, 4), 256, 0, stream>>>(big1, a1, ni, nj, N_NODES);
  k_logit<<<EB, 256, 0, stream>>>(src, dst, et, ni, nj, rs, logit, N_EDGES);
  k_aggregate<1><<<N_NODES, 128, 0, stream>>>(off, csr, src, logit, h16, alpha0, big2, N_NODES);

  // ---- head ----
  k_gemm_mfma<true, false><<<GB, 256, 0, stream>>>(big2, wph, wpl, pool_b, big1, nullptr, N_NODES, 128);
  k_out<<<cdiv(N_NODES, 4), 256, 0, stream>>>(big1, out_w, out_b, (float*)d_out, N_NODES);
}